// Round 6
// baseline (459.622 us; speedup 1.0000x reference)
//
#include <hip/hip_runtime.h>

// Problem constants (match reference setup_inputs)
constexpr int B = 64, T = 256, M = 16, A = 32, H = 64;
constexpr int NGP = 84;   // 81 used groups (16 J + 64 R + 1 o) padded to 84 (DMA gathers 4 at a time)
constexpr int NG = 81;

// G layout (group-major): G[((size_t)g * rows + r) * 64 + c]
//   g in [0,81): 0-15 = J groups, 16-79 = R rows, 80 = out-gate
//   r = b * chunk + tc (row within the time-chunk), c = output column k
// Scan DMAs 4 groups per global_load_lds; LDS image is buf[g*64 + c].

// ---------------------------------------------------------------------------
// Gate kernel v6: thread = row (proven no-spill). acc[64] in regs, softmax
// thread-local, W broadcast from LDS. Group-major stores: 4 contiguous
// dwordx4 per thread, no transpose, no bank conflicts.
// ---------------------------------------------------------------------------
__device__ __forceinline__ void softmax64(float (&acc)[64]) {
    float t32[32];
    #pragma unroll
    for (int i = 0; i < 32; ++i) t32[i] = fmaxf(acc[i], acc[i + 32]);
    #pragma unroll
    for (int i = 0; i < 16; ++i) t32[i] = fmaxf(t32[i], t32[i + 16]);
    #pragma unroll
    for (int i = 0; i < 8; ++i)  t32[i] = fmaxf(t32[i], t32[i + 8]);
    #pragma unroll
    for (int i = 0; i < 4; ++i)  t32[i] = fmaxf(t32[i], t32[i + 4]);
    float mx = fmaxf(fmaxf(t32[0], t32[1]), fmaxf(t32[2], t32[3]));
    float s0 = 0.f, s1 = 0.f, s2 = 0.f, s3 = 0.f;
    #pragma unroll
    for (int i = 0; i < 16; ++i) {
        acc[4*i+0] = __expf(acc[4*i+0] - mx); s0 += acc[4*i+0];
        acc[4*i+1] = __expf(acc[4*i+1] - mx); s1 += acc[4*i+1];
        acc[4*i+2] = __expf(acc[4*i+2] - mx); s2 += acc[4*i+2];
        acc[4*i+3] = __expf(acc[4*i+3] - mx); s3 += acc[4*i+3];
    }
    float inv = 1.f / ((s0 + s1) + (s2 + s3));
    #pragma unroll
    for (int c = 0; c < 64; ++c) acc[c] *= inv;
}

__global__ __launch_bounds__(256, 2) void gate_kernel(
    const float* __restrict__ x_a,
    const float* __restrict__ Wj, const float* __restrict__ bj,
    const float* __restrict__ Wr, const float* __restrict__ br,
    const float* __restrict__ Wo, const float* __restrict__ bo,
    float* __restrict__ G, int t0, int chunk)
{
    const int g = blockIdx.x;
    const int tid = threadIdx.x;
    const int rows = B * chunk;

    __shared__ float4 W4[512];          // 8KB: W[c] row-quad j at W4[c*8+j]
    __shared__ float bs[64];

    const float* Wp; const float* bp; int row0;
    if (g < 16)      { Wp = Wj; bp = bj; row0 = g * H; }
    else if (g < 80) { Wp = Wr; bp = br; row0 = (g - 16) * H; }
    else             { Wp = Wo; bp = bo; row0 = 0; }

    {   // cooperative W stage + bias
        const float4* src = (const float4*)(Wp + (size_t)row0 * A);
        W4[tid * 2]     = src[tid * 2];
        W4[tid * 2 + 1] = src[tid * 2 + 1];
        if (tid < 64) bs[tid] = bp[row0 + tid];
    }

    const int r0 = blockIdx.y * 256 + tid;
    const int bb = r0 / chunk, tcc = r0 % chunk;
    float4 xa[8];
    {
        const float4* src = (const float4*)(x_a + ((size_t)bb * T + t0 + tcc) * A);
        #pragma unroll
        for (int j = 0; j < 8; ++j) xa[j] = src[j];
    }
    __syncthreads();

    float acc[64];
    #pragma unroll
    for (int c = 0; c < 64; ++c) {
        float s = bs[c];
        #pragma unroll
        for (int j = 0; j < 8; ++j) {
            float4 w = W4[c * 8 + j];   // wave-uniform -> LDS broadcast
            s += xa[j].x * w.x + xa[j].y * w.y + xa[j].z * w.z + xa[j].w * w.w;
        }
        acc[c] = s;
    }

    if (g < 80) { softmax64(acc); }
    else {
        #pragma unroll
        for (int c = 0; c < 64; ++c) acc[c] = 1.f / (1.f + __expf(-acc[c]));
    }

    // group-major store: 4 contiguous dwordx4, 256B per thread
    float4* dst = (float4*)(G + ((size_t)g * rows + r0) * 64);
    #pragma unroll
    for (int j = 0; j < 16; ++j)
        dst[j] = make_float4(acc[4*j], acc[4*j+1], acc[4*j+2], acc[4*j+3]);
}

// ---------------------------------------------------------------------------
// Scan kernel v7.1: one wave per batch. Per step, 21 global_load_lds gather
// 84 groups x 256B into LDS (triple-buffered, counted vmcnt). Lane l =
// (k-quad q=l&15, h-range hr=l>>4); b128 LDS reads; shfl_xor reduce.
// ---------------------------------------------------------------------------
__global__ __launch_bounds__(64, 1) void scan_kernel(
    const float* __restrict__ G,
    const float* __restrict__ x_m,
    const float* __restrict__ Wfc, const float* __restrict__ bfc,
    float* __restrict__ out, int t0, int chunk, int first)
{
    const int b = blockIdx.x;
    const int l = threadIdx.x;
    const int q = l & 15;    // k-quad: k = 4q..4q+3
    const int hr = l >> 4;   // h-range: h = hr*16 .. hr*16+15
    const int rows = B * chunk;
    const size_t rows64 = (size_t)rows * 64;

    __shared__ __align__(16) float buf[3][NGP * 64];  // 63KB triple buffer
    __shared__ __align__(16) float c_sh[64];
    __shared__ __align__(16) float xm_s[1024];        // chunk<=64

    float* cbase = out + B;  // c region: cbase[(b*T + t)*H + k]

    {   // stage x_m chunk (chunk*16 floats)
        const float4* src = (const float4*)(x_m + ((size_t)b * T + t0) * M);
        float4* dst = (float4*)xm_s;
        for (int i = l; i < chunk * 4; i += 64) dst[i] = src[i];
    }
    c_sh[l] = first ? 0.f : cbase[((size_t)b * T + (t0 - 1)) * H + l];
    const float4 wfc4 = *(const float4*)&Wfc[q * 4];
    const float bfc0 = bfc[0];

    // per-lane gather offset: group-subindex (l>>4) and col-quad (l&15)
    const size_t laneoff = (size_t)hr * rows64 + (size_t)q * 4;
    asm volatile("s_waitcnt vmcnt(0) lgkmcnt(0)" ::: "memory");

#define DMA(tc_)                                                                \
    {                                                                           \
        const float* rp_ = G + (size_t)(b * chunk + (tc_)) * 64 + laneoff;      \
        float* lb_ = &buf[(tc_) % 3][0];                                        \
        _Pragma("unroll")                                                       \
        for (int i_ = 0; i_ < 21; ++i_)                                         \
            __builtin_amdgcn_global_load_lds(                                   \
                (const __attribute__((address_space(1))) unsigned int*)         \
                    (rp_ + (size_t)(4 * i_) * rows64),                          \
                (__attribute__((address_space(3))) unsigned int*)               \
                    (lb_ + i_ * 256), 16, 0, 0);                                \
    }

    DMA(0); DMA(1); DMA(2);

    for (int tc = 0; tc < chunk; ++tc) {
        // counted waits: conservative (store insts add slack, never deficit)
        if (tc + 3 <= chunk)      asm volatile("s_waitcnt vmcnt(42)" ::: "memory");
        else if (tc + 2 == chunk) asm volatile("s_waitcnt vmcnt(21)" ::: "memory");
        else                      asm volatile("s_waitcnt vmcnt(0)"  ::: "memory");
        __builtin_amdgcn_sched_barrier(0);

        const float* bp2 = &buf[tc % 3][0];

        float cc[16];
        #pragma unroll
        for (int i = 0; i < 16; ++i) cc[i] = c_sh[hr * 16 + i];
        float xm[4];
        #pragma unroll
        for (int j = 0; j < 4; ++j) xm[j] = xm_s[tc * 16 + hr * 4 + j];

        float a0 = 0.f, a1 = 0.f, a2 = 0.f, a3 = 0.f;
        #pragma unroll
        for (int j = 0; j < 4; ++j) {
            const float4 jv = *(const float4*)&bp2[(hr * 4 + j) * 64 + q * 4];
            a0 += xm[j] * jv.x; a1 += xm[j] * jv.y;
            a2 += xm[j] * jv.z; a3 += xm[j] * jv.w;
        }
        #pragma unroll
        for (int i = 0; i < 16; ++i) {
            const float4 rv = *(const float4*)&bp2[1024 + (hr * 16 + i) * 64 + q * 4];
            a0 += cc[i] * rv.x; a1 += cc[i] * rv.y;
            a2 += cc[i] * rv.z; a3 += cc[i] * rv.w;
        }
        const float4 o4 = *(const float4*)&bp2[5120 + q * 4];

        // reduce partials across the 4 h-ranges (lanes ^16, ^32)
        a0 += __shfl_xor(a0, 16); a1 += __shfl_xor(a1, 16);
        a2 += __shfl_xor(a2, 16); a3 += __shfl_xor(a3, 16);
        a0 += __shfl_xor(a0, 32); a1 += __shfl_xor(a1, 32);
        a2 += __shfl_xor(a2, 32); a3 += __shfl_xor(a3, 32);

        const float cn0 = (1.f - o4.x) * a0;
        const float cn1 = (1.f - o4.y) * a1;
        const float cn2 = (1.f - o4.z) * a2;
        const float cn3 = (1.f - o4.w) * a3;

        if (hr == 0) {   // 16 lanes: write c_sh + coalesced 256B global store
            *(float4*)&c_sh[q * 4] = make_float4(cn0, cn1, cn2, cn3);
            *(float4*)(cbase + ((size_t)b * T + t0 + tc) * H + q * 4) =
                make_float4(cn0, cn1, cn2, cn3);
        }
        if (t0 + tc == T - 1) {  // fused fc on last timestep
            float v = o4.x * a0 * wfc4.x + o4.y * a1 * wfc4.y +
                      o4.z * a2 * wfc4.z + o4.w * a3 * wfc4.w;
            v += __shfl_xor(v, 1); v += __shfl_xor(v, 2);
            v += __shfl_xor(v, 4); v += __shfl_xor(v, 8);
            if (l == 0) out[b] = v + bfc0;
        }

        if (tc + 3 < chunk) {
            asm volatile("s_waitcnt lgkmcnt(0)" ::: "memory");  // LDS reads done
            DMA(tc + 3);
        }
    }
#undef DMA
}

// ---------------------------------------------------------------------------
extern "C" void kernel_launch(void* const* d_in, const int* in_sizes, int n_in,
                              void* d_out, int out_size, void* d_ws, size_t ws_size,
                              hipStream_t stream) {
    const float* x_m = (const float*)d_in[0];
    const float* x_a = (const float*)d_in[1];
    const float* Wj  = (const float*)d_in[2];
    const float* bj  = (const float*)d_in[3];
    const float* Wr  = (const float*)d_in[4];
    const float* br  = (const float*)d_in[5];
    const float* Wo  = (const float*)d_in[6];
    const float* bo  = (const float*)d_in[7];
    const float* Wfc = (const float*)d_in[8];
    const float* bfc = (const float*)d_in[9];
    float* out = (float*)d_out;
    float* G   = (float*)d_ws;

    // time-chunk: prefer 64 (88MB G incl. 84-group pad), shrink to fit ws
    int chunk = 64;
    while (chunk > 8 && (size_t)NGP * (B * chunk) * 64 * sizeof(float) > ws_size)
        chunk >>= 1;

    for (int t0 = 0; t0 < T; t0 += chunk) {
        gate_kernel<<<dim3(NG, (B * chunk) / 256), 256, 0, stream>>>(
            x_a, Wj, bj, Wr, br, Wo, bo, G, t0, chunk);
        scan_kernel<<<64, 64, 0, stream>>>(
            G, x_m, Wfc, bfc, out, t0, chunk, t0 == 0 ? 1 : 0);
    }
}

// Round 7
// 447.837 us; speedup vs baseline: 1.0263x; 1.0263x over previous
//
#include <hip/hip_runtime.h>

// Problem constants (match reference setup_inputs)
constexpr int B = 64, T = 256, M = 16, A = 32, H = 64;
constexpr int NCOL  = M * H + H * H + H;  // 1024 + 4096 + 64 = 5184 used cols
constexpr int NCOLP = 5376;               // padded row stride: 21504 B = 21 x 1KB DMA
constexpr int NG = 81;                    // 16 J + 64 R + 1 o groups of 64 cols

// G layout (row-major): G[r * NCOLP + g*64 + c], r = b*chunk + tc.
// Row image: [J 1024 | R 4096 | o 64 | pad 192] -- exactly what scan DMAs.

// ---------------------------------------------------------------------------
// Gate kernel v8: thread = row (no-spill structure). acc[64] in regs,
// softmax thread-local, W broadcast from LDS. Store via per-wave LDS tile
// [64][68] (stride 68 floats = conflict-free both phases), read out as
// 4x256B fully-coalesced runs per store instruction.
// ---------------------------------------------------------------------------
__device__ __forceinline__ void softmax64(float (&acc)[64]) {
    float t32[32];
    #pragma unroll
    for (int i = 0; i < 32; ++i) t32[i] = fmaxf(acc[i], acc[i + 32]);
    #pragma unroll
    for (int i = 0; i < 16; ++i) t32[i] = fmaxf(t32[i], t32[i + 16]);
    #pragma unroll
    for (int i = 0; i < 8; ++i)  t32[i] = fmaxf(t32[i], t32[i + 8]);
    #pragma unroll
    for (int i = 0; i < 4; ++i)  t32[i] = fmaxf(t32[i], t32[i + 4]);
    float mx = fmaxf(fmaxf(t32[0], t32[1]), fmaxf(t32[2], t32[3]));
    float s0 = 0.f, s1 = 0.f, s2 = 0.f, s3 = 0.f;
    #pragma unroll
    for (int i = 0; i < 16; ++i) {
        acc[4*i+0] = __expf(acc[4*i+0] - mx); s0 += acc[4*i+0];
        acc[4*i+1] = __expf(acc[4*i+1] - mx); s1 += acc[4*i+1];
        acc[4*i+2] = __expf(acc[4*i+2] - mx); s2 += acc[4*i+2];
        acc[4*i+3] = __expf(acc[4*i+3] - mx); s3 += acc[4*i+3];
    }
    float inv = 1.f / ((s0 + s1) + (s2 + s3));
    #pragma unroll
    for (int c = 0; c < 64; ++c) acc[c] *= inv;
}

__global__ __launch_bounds__(256, 2) void gate_kernel(
    const float* __restrict__ x_a,
    const float* __restrict__ Wj, const float* __restrict__ bj,
    const float* __restrict__ Wr, const float* __restrict__ br,
    const float* __restrict__ Wo, const float* __restrict__ bo,
    float* __restrict__ G, int t0, int chunk)
{
    const int g = blockIdx.x;
    const int tid = threadIdx.x;
    const int lane = tid & 63;
    const int wv = tid >> 6;

    __shared__ float4 W4[512];            // 8KB: W[c] row-quad j at W4[c*8+j]
    __shared__ float bs[64];
    __shared__ float tile[4][64][68];     // 69.6KB per-wave transpose tiles

    const float* Wp; const float* bp; int row0;
    if (g < 16)      { Wp = Wj; bp = bj; row0 = g * H; }
    else if (g < 80) { Wp = Wr; bp = br; row0 = (g - 16) * H; }
    else             { Wp = Wo; bp = bo; row0 = 0; }

    {   // cooperative W stage + bias
        const float4* src = (const float4*)(Wp + (size_t)row0 * A);
        W4[tid * 2]     = src[tid * 2];
        W4[tid * 2 + 1] = src[tid * 2 + 1];
        if (tid < 64) bs[tid] = bp[row0 + tid];
    }

    const int r0 = blockIdx.y * 256 + tid;      // this thread's row
    const int bb = r0 / chunk, tcc = r0 % chunk;
    float4 xa[8];
    {
        const float4* src = (const float4*)(x_a + ((size_t)bb * T + t0 + tcc) * A);
        #pragma unroll
        for (int j = 0; j < 8; ++j) xa[j] = src[j];
    }
    __syncthreads();

    float acc[64];
    #pragma unroll
    for (int c = 0; c < 64; ++c) {
        float s = bs[c];
        #pragma unroll
        for (int j = 0; j < 8; ++j) {
            float4 w = W4[c * 8 + j];   // wave-uniform -> LDS broadcast
            s += xa[j].x * w.x + xa[j].y * w.y + xa[j].z * w.z + xa[j].w * w.w;
        }
        acc[c] = s;
    }

    if (g < 80) { softmax64(acc); }
    else {
        #pragma unroll
        for (int c = 0; c < 64; ++c) acc[c] = 1.f / (1.f + __expf(-acc[c]));
    }

    // ---- store via per-wave LDS tile ----
    // write phase: lane = local row; quad q at float offset lane*68 + 4q.
    // start bank-group = (lane+q) mod 8 -> 8 lanes per group: conflict-free.
    #pragma unroll
    for (int q = 0; q < 16; ++q)
        *(float4*)&tile[wv][lane][q * 4] =
            make_float4(acc[4*q], acc[4*q+1], acc[4*q+2], acc[4*q+3]);

    // order same-wave DS writes before DS reads (cross-lane dep invisible
    // to compiler); wave-lockstep + in-order DS pipe makes HW side safe.
    asm volatile("s_waitcnt lgkmcnt(0)" ::: "memory");
    __builtin_amdgcn_sched_barrier(0);

    // read+store phase: lane = (row-quad rloc = l>>4, col-quad qq = l&15).
    // Each store inst covers 4 complete 256B row-segments (fully coalesced).
    const int rloc = lane >> 4, qq = lane & 15;
    const int rowg = blockIdx.y * 256 + wv * 64;
    #pragma unroll
    for (int i = 0; i < 16; ++i) {
        const int rr = rloc + 4 * i;
        float4 v = *(const float4*)&tile[wv][rr][qq * 4];
        *(float4*)(G + (size_t)(rowg + rr) * NCOLP + g * 64 + qq * 4) = v;
    }
}

// ---------------------------------------------------------------------------
// Scan kernel v7 (R5-proven): one wave per batch. G-row async-DMA'd to LDS
// (global_load_lds dwordx4, triple-buffered, counted vmcnt -- never 0
// mid-loop). Lane l = (k-quad q=l&15, h-range hr=l>>4); b128 LDS reads;
// in-wave shfl_xor reduce. No barriers, no register pressure.
// ---------------------------------------------------------------------------
__global__ __launch_bounds__(64, 1) void scan_kernel(
    const float* __restrict__ G,
    const float* __restrict__ x_m,
    const float* __restrict__ Wfc, const float* __restrict__ bfc,
    float* __restrict__ out, int t0, int chunk, int first)
{
    const int b = blockIdx.x;
    const int l = threadIdx.x;
    const int q = l & 15;    // k-quad: k = 4q..4q+3
    const int hr = l >> 4;   // h-range: h = hr*16 .. hr*16+15

    __shared__ __align__(16) float buf[3][NCOLP];   // 63KB triple buffer
    __shared__ __align__(16) float c_sh[64];
    __shared__ __align__(16) float xm_s[1024];      // chunk<=64

    float* cbase = out + B;  // c region: cbase[(b*T + t)*H + k]

    {   // stage x_m chunk (chunk*16 floats)
        const float4* src = (const float4*)(x_m + ((size_t)b * T + t0) * M);
        float4* dst = (float4*)xm_s;
        for (int i = l; i < chunk * 4; i += 64) dst[i] = src[i];
    }
    c_sh[l] = first ? 0.f : cbase[((size_t)b * T + (t0 - 1)) * H + l];
    const float4 wfc4 = *(const float4*)&Wfc[q * 4];
    const float bfc0 = bfc[0];
    asm volatile("s_waitcnt vmcnt(0) lgkmcnt(0)" ::: "memory");

#define DMA(tc_)                                                                \
    {                                                                           \
        const float* rp_ = G + (size_t)(b * chunk + (tc_)) * NCOLP;             \
        float* lb_ = &buf[(tc_) % 3][0];                                        \
        _Pragma("unroll")                                                       \
        for (int i_ = 0; i_ < 21; ++i_)                                         \
            __builtin_amdgcn_global_load_lds(                                   \
                (const __attribute__((address_space(1))) unsigned int*)         \
                    (rp_ + i_ * 256 + l * 4),                                   \
                (__attribute__((address_space(3))) unsigned int*)               \
                    (lb_ + i_ * 256), 16, 0, 0);                                \
    }

    DMA(0); DMA(1); DMA(2);

    for (int tc = 0; tc < chunk; ++tc) {
        // counted waits: conservative (store insts add slack, never deficit)
        if (tc + 3 <= chunk)      asm volatile("s_waitcnt vmcnt(42)" ::: "memory");
        else if (tc + 2 == chunk) asm volatile("s_waitcnt vmcnt(21)" ::: "memory");
        else                      asm volatile("s_waitcnt vmcnt(0)"  ::: "memory");
        __builtin_amdgcn_sched_barrier(0);

        const float* bp2 = &buf[tc % 3][0];

        float cc[16];
        #pragma unroll
        for (int i = 0; i < 16; ++i) cc[i] = c_sh[hr * 16 + i];
        float xm[4];
        #pragma unroll
        for (int j = 0; j < 4; ++j) xm[j] = xm_s[tc * 16 + hr * 4 + j];

        float a0 = 0.f, a1 = 0.f, a2 = 0.f, a3 = 0.f;
        #pragma unroll
        for (int j = 0; j < 4; ++j) {
            const float4 jv = *(const float4*)&bp2[(hr * 4 + j) * 64 + q * 4];
            a0 += xm[j] * jv.x; a1 += xm[j] * jv.y;
            a2 += xm[j] * jv.z; a3 += xm[j] * jv.w;
        }
        #pragma unroll
        for (int i = 0; i < 16; ++i) {
            const float4 rv = *(const float4*)&bp2[1024 + (hr * 16 + i) * 64 + q * 4];
            a0 += cc[i] * rv.x; a1 += cc[i] * rv.y;
            a2 += cc[i] * rv.z; a3 += cc[i] * rv.w;
        }
        const float4 o4 = *(const float4*)&bp2[5120 + q * 4];

        // reduce partials across the 4 h-ranges (lanes ^16, ^32)
        a0 += __shfl_xor(a0, 16); a1 += __shfl_xor(a1, 16);
        a2 += __shfl_xor(a2, 16); a3 += __shfl_xor(a3, 16);
        a0 += __shfl_xor(a0, 32); a1 += __shfl_xor(a1, 32);
        a2 += __shfl_xor(a2, 32); a3 += __shfl_xor(a3, 32);

        const float cn0 = (1.f - o4.x) * a0;
        const float cn1 = (1.f - o4.y) * a1;
        const float cn2 = (1.f - o4.z) * a2;
        const float cn3 = (1.f - o4.w) * a3;

        if (hr == 0) {   // 16 lanes: write c_sh + coalesced 256B global store
            *(float4*)&c_sh[q * 4] = make_float4(cn0, cn1, cn2, cn3);
            *(float4*)(cbase + ((size_t)b * T + t0 + tc) * H + q * 4) =
                make_float4(cn0, cn1, cn2, cn3);
        }
        if (t0 + tc == T - 1) {  // fused fc on last timestep
            float v = o4.x * a0 * wfc4.x + o4.y * a1 * wfc4.y +
                      o4.z * a2 * wfc4.z + o4.w * a3 * wfc4.w;
            v += __shfl_xor(v, 1); v += __shfl_xor(v, 2);
            v += __shfl_xor(v, 4); v += __shfl_xor(v, 8);
            if (l == 0) out[b] = v + bfc0;
        }

        if (tc + 3 < chunk) {
            asm volatile("s_waitcnt lgkmcnt(0)" ::: "memory");  // LDS reads done
            DMA(tc + 3);
        }
    }
#undef DMA
}

// ---------------------------------------------------------------------------
extern "C" void kernel_launch(void* const* d_in, const int* in_sizes, int n_in,
                              void* d_out, int out_size, void* d_ws, size_t ws_size,
                              hipStream_t stream) {
    const float* x_m = (const float*)d_in[0];
    const float* x_a = (const float*)d_in[1];
    const float* Wj  = (const float*)d_in[2];
    const float* bj  = (const float*)d_in[3];
    const float* Wr  = (const float*)d_in[4];
    const float* br  = (const float*)d_in[5];
    const float* Wo  = (const float*)d_in[6];
    const float* bo  = (const float*)d_in[7];
    const float* Wfc = (const float*)d_in[8];
    const float* bfc = (const float*)d_in[9];
    float* out = (float*)d_out;
    float* G   = (float*)d_ws;

    // time-chunk: prefer 64 (88MB G), shrink to fit ws; keep >= 8
    int chunk = 64;
    while (chunk > 8 && (size_t)B * chunk * NCOLP * sizeof(float) > ws_size) chunk >>= 1;

    for (int t0 = 0; t0 < T; t0 += chunk) {
        gate_kernel<<<dim3(NG, (B * chunk) / 256), 256, 0, stream>>>(
            x_a, Wj, bj, Wr, br, Wo, bo, G, t0, chunk);
        scan_kernel<<<64, 64, 0, stream>>>(
            G, x_m, Wfc, bfc, out, t0, chunk, t0 == 0 ? 1 : 0);
    }
}